// Round 7
// baseline (915.477 us; speedup 1.0000x reference)
//
#include <hip/hip_runtime.h>
#include <hip/hip_bf16.h>
#include <hip/hip_cooperative_groups.h>

namespace cg = cooperative_groups;

// PatchGINEncoder on MI355X.
// R1-R13: see git history. Key: int32 edge inputs; col[node][64] buckets built
//     by sliced atomic scatter in k_setup; fused per-layer aggregate+MLP(MFMA).
// R14 (FAILED): 8-deep gather @ VGPR 68: occupancy cliff, slower.
// R15: 32-row tiles, 4-deep gather, VGPR 40. (476us)
// R16/R17: scatter chunks 2048, interleaved bid%3. k_setup < 85us.
// R18 (FAILED, decisive): 8-deep @ VGPR 56: dur/BW FLAT, occ 53->37%.
//     Gather = per-CU miss-slot (Q~32) x latency bound; FETCH ~193MB is the
//     compulsory floor (random graph: each XCD touches each src row ~once).
//     k_layer ~85us STRUCTURAL at bf16.
// R19/R20 (FAILED): 64 slice-owner full-E scans: occ 4%, k_setup ~1150us.
// R21: revert + fused fill/hga memset: 472.3us BEST. One fewer dispatch
//     = -3.6us => per-dispatch overhead ~4us. Unattributed time ~100us.
// R22: cooperative mega-kernel: 3x k_layer + k_pool + k_proj_ln fused into
//     one persistent kernel (grid-stride tiles, 4x grid.sync). Tests the
//     dispatch-boundary theory: 7 -> 3 dispatches. Grid clamped by
//     occupancy query (cooperative co-residency guaranteed); R15/R18 show
//     gather is insensitive to block count, so grid<3125 is ~free.

#define GDEPTH 3
#define CAP 64
#define PCH 128

typedef __bf16 bf16x8 __attribute__((ext_vector_type(8)));
typedef float  f32x4  __attribute__((ext_vector_type(4)));
typedef __hip_bfloat16  bf16;
typedef __hip_bfloat162 bf162;

#define CSR_CH 2048
#define NSLICE 8
#define NSLICE_LOG 3

// ------- fused setup: bucket scatter (interleaved) | prep | convert x | bounds ----
__global__ void k_setup(const float* __restrict__ W1s, const float* __restrict__ W2s,
                        const float* __restrict__ b1s, const float* __restrict__ bng,
                        const float* __restrict__ bnb, const float* __restrict__ bnm,
                        const float* __restrict__ bnv,
                        bf16* __restrict__ Wp1, bf16* __restrict__ Wp2,
                        float* __restrict__ sArr, float* __restrict__ tArr,
                        const float4* __restrict__ x4, bf162* __restrict__ h,
                        const int* __restrict__ batch, int* __restrict__ gp,
                        const int* __restrict__ ei, int* __restrict__ fill,
                        int* __restrict__ col,
                        int N, int E, int G, int BCONV, int BGB, int BCSR) {
    int bid = blockIdx.x;
    int tid = threadIdx.x;
    if (bid % 3 == 0 && bid / 3 < BCSR) {
        // ---- sliced bucket scatter (atomic/write locality), int4 edge reads ----
        int sb = bid / 3;
        int s = sb & (NSLICE - 1);
        int chunk = sb >> NSLICE_LOG;
        int lo = (int)((long long)s * N / NSLICE);
        int hi = (int)((long long)(s + 1) * N / NSLICE);
        int baseq = chunk * (CSR_CH / 4);
        const int4* d4p = (const int4*)(ei + E);
        const int4* s4p = (const int4*)ei;
        #pragma unroll
        for (int i = 0; i < CSR_CH / 1024; ++i) {
            int q = baseq + i * 256 + tid;
            int e0 = q * 4;
            if (e0 + 3 < E) {
                int4 d4 = d4p[q];
                if ((d4.x >= lo && d4.x < hi) || (d4.y >= lo && d4.y < hi) ||
                    (d4.z >= lo && d4.z < hi) || (d4.w >= lo && d4.w < hi)) {
                    int4 s4 = s4p[q];
                    if (d4.x >= lo && d4.x < hi) { int p = atomicAdd(&fill[d4.x], 1); if (p < CAP) col[(size_t)d4.x * CAP + p] = s4.x; }
                    if (d4.y >= lo && d4.y < hi) { int p = atomicAdd(&fill[d4.y], 1); if (p < CAP) col[(size_t)d4.y * CAP + p] = s4.y; }
                    if (d4.z >= lo && d4.z < hi) { int p = atomicAdd(&fill[d4.z], 1); if (p < CAP) col[(size_t)d4.z * CAP + p] = s4.z; }
                    if (d4.w >= lo && d4.w < hi) { int p = atomicAdd(&fill[d4.w], 1); if (p < CAP) col[(size_t)d4.w * CAP + p] = s4.w; }
                }
            } else if (e0 < E) {
                for (int e = e0; e < E; ++e) {
                    int d = ei[E + e];
                    if (d >= lo && d < hi) {
                        int p = atomicAdd(&fill[d], 1);
                        if (p < CAP) col[(size_t)d * CAP + p] = ei[e];
                    }
                }
            }
        }
        return;
    }
    // compact non-scatter block id: subtract # of scatter bids < bid
    {
        int nsc = (bid + 2) / 3;
        if (nsc > BCSR) nsc = BCSR;
        bid -= nsc;
    }
    if (bid < 384) {
        // ---- weight prep: pack W into B-frag order, fold BN ----
        int idx = bid * 256 + tid;                 // [0, 6*16384)
        int l   = idx / 32768;
        int rem = idx - l * 32768;
        int w   = rem >> 14;
        int p   = rem & 16383;
        int j = p & 7, n = (p >> 3) & 127, tq = p >> 10;
        int quad = tq & 3, kk = tq >> 2;
        int k = kk * 32 + quad * 8 + j;
        const float* W = w ? W2s : W1s;
        bf16* Wp = w ? Wp2 : Wp1;
        Wp[l * 16384 + p] = __float2bfloat16(W[l * 16384 + k * 128 + n]);
        if (idx < GDEPTH * 128) {
            int ll = idx >> 7, c = idx & 127;
            float inv = rsqrtf(bnv[ll * 128 + c] + 1e-5f);
            float s = inv * bng[ll * 128 + c];
            sArr[idx] = s;
            tArr[idx] = (b1s[ll * 128 + c] - bnm[ll * 128 + c]) * s + bnb[ll * 128 + c];
        }
        return;
    }
    bid -= 384;
    if (bid < BCONV) {
        // ---- x -> bf16 ----
        int i = bid * 256 + tid;
        int n4 = N * 32;
        if (i < n4) {
            float4 v = x4[i];
            bf162 a, b;
            a.x = __float2bfloat16(v.x); a.y = __float2bfloat16(v.y);
            b.x = __float2bfloat16(v.z); b.y = __float2bfloat16(v.w);
            h[2 * i] = a; h[2 * i + 1] = b;
        }
        return;
    }
    bid -= BCONV;
    if (bid < BGB) {
        // ---- graph bounds from sorted batch ----
        int i = bid * 256 + tid;
        if (i < N) {
            int b = batch[i];
            if (i == 0) {
                for (int g = 0; g <= b; ++g) gp[g] = 0;
            } else {
                int pb = batch[i - 1];
                if (pb != b) for (int g = pb + 1; g <= b; ++g) gp[g] = i;
            }
            if (i == N - 1) {
                for (int g = b + 1; g <= G; ++g) gp[g] = N;
            }
        }
        return;
    }
}

// -------- cooperative mega kernel: 3x layer + pool + proj/LN ----------------
// Layer tile body is the verified k_layer (R15/R21) with m0 = tile*32 and a
// trailing barrier so As can be reused by the next grid-stride tile.
__global__ __launch_bounds__(256, 4) void k_mega(
        bf16* __restrict__ bufA, bf16* __restrict__ bufB,
        const int* __restrict__ deg, const int* __restrict__ col,
        const bf16* __restrict__ Wp1, const bf16* __restrict__ Wp2,
        const float* __restrict__ sAr, const float* __restrict__ tAr,
        const float* __restrict__ b2s,
        const int* __restrict__ batch, const int* __restrict__ gp,
        float* __restrict__ hga,
        const float* __restrict__ Wpj, const float* __restrict__ bpj,
        const float* __restrict__ lng, const float* __restrict__ lnb,
        float* __restrict__ outp,
        int N, int G, int NT, int NB) {
    cg::grid_group gg = cg::this_grid();
    __shared__ __align__(16) char smem[32 * 136 * 2];   // As | prow/pred alias
    bf16* As = (bf16*)smem;
    const int tid = threadIdx.x;

    // ---------------- 3 layers ----------------
    for (int l = 0; l < GDEPTH; ++l) {
        const bf16* h = (l & 1) ? bufB : bufA;
        bf16* Out = (l & 1) ? bufA : bufB;
        const bf16* Bp1 = Wp1 + (size_t)l * 16384;
        const bf16* Bp2 = Wp2 + (size_t)l * 16384;
        const float* sv = sAr + l * 128;
        const float* tv = tAr + l * 128;
        const float* b2 = b2s + l * 128;
        const bf16x8* h8 = (const bf16x8*)h;

        for (int tile = blockIdx.x; tile < NT; tile += NB) {
            const int m0 = tile * 32;
            const int grp = tid >> 4, c = tid & 15;
            #pragma unroll
            for (int it = 0; it < 2; ++it) {
                int row = grp * 2 + it;
                int node = m0 + row;
                float acc[8];
                if (node < N) {
                    bf16x8 self = h8[(size_t)node * 16 + c];
                    #pragma unroll
                    for (int k = 0; k < 8; ++k) acc[k] = (float)self[k];
                    int d = deg[node]; if (d > CAP) d = CAP;
                    const int* cb = col + (size_t)node * CAP;
                    int e = 0;
                    for (; e + 3 < d; e += 4) {
                        int j0 = cb[e], j1 = cb[e + 1], j2 = cb[e + 2], j3 = cb[e + 3];
                        bf16x8 v0 = h8[(size_t)j0 * 16 + c];
                        bf16x8 v1 = h8[(size_t)j1 * 16 + c];
                        bf16x8 v2 = h8[(size_t)j2 * 16 + c];
                        bf16x8 v3 = h8[(size_t)j3 * 16 + c];
                        #pragma unroll
                        for (int k = 0; k < 8; ++k)
                            acc[k] += ((float)v0[k] + (float)v1[k]) + ((float)v2[k] + (float)v3[k]);
                    }
                    for (; e < d; ++e) {
                        bf16x8 v = h8[(size_t)cb[e] * 16 + c];
                        #pragma unroll
                        for (int k = 0; k < 8; ++k) acc[k] += (float)v[k];
                    }
                } else {
                    #pragma unroll
                    for (int k = 0; k < 8; ++k) acc[k] = 0.f;
                }
                bf16x8 r;
                #pragma unroll
                for (int k = 0; k < 8; ++k) {
                    __hip_bfloat16 t = __float2bfloat16(acc[k]);
                    r[k] = *(__bf16*)&t;
                }
                *(bf16x8*)(As + row * 136 + c * 8) = r;
            }
            __syncthreads();

            const int lane = tid & 63;
            const int wid = tid >> 6;
            const int wm = wid & 1, wn = wid >> 1;
            const int l15 = lane & 15, quad = lane >> 4;

            f32x4 acc[4];
            #pragma unroll
            for (int j = 0; j < 4; ++j) acc[j] = (f32x4){0.f, 0.f, 0.f, 0.f};
            #pragma unroll
            for (int kk = 0; kk < 4; ++kk) {
                bf16x8 a, b[4];
                #pragma unroll
                for (int tn = 0; tn < 4; ++tn)
                    b[tn] = *(const bf16x8*)(Bp1 + ((kk * 4 + quad) * 128 + wn * 64 + tn * 16 + l15) * 8);
                a = *(const bf16x8*)(As + (wm * 16 + l15) * 136 + kk * 32 + quad * 8);
                #pragma unroll
                for (int tn = 0; tn < 4; ++tn)
                    acc[tn] = __builtin_amdgcn_mfma_f32_16x16x32_bf16(a, b[tn], acc[tn], 0, 0, 0);
            }
            __syncthreads();
            #pragma unroll
            for (int tn = 0; tn < 4; ++tn) {
                int gc = wn * 64 + tn * 16 + l15;
                float scale = sv[gc], shift = tv[gc];
                #pragma unroll
                for (int r = 0; r < 4; ++r) {
                    float v = fmaxf(acc[tn][r] * scale + shift, 0.f);
                    int row = wm * 16 + quad * 4 + r;
                    __hip_bfloat16 t = __float2bfloat16(v);
                    As[row * 136 + gc] = *(bf16*)&t;
                }
            }
            __syncthreads();
            #pragma unroll
            for (int j = 0; j < 4; ++j) acc[j] = (f32x4){0.f, 0.f, 0.f, 0.f};
            #pragma unroll
            for (int kk = 0; kk < 4; ++kk) {
                bf16x8 a, b[4];
                #pragma unroll
                for (int tn = 0; tn < 4; ++tn)
                    b[tn] = *(const bf16x8*)(Bp2 + ((kk * 4 + quad) * 128 + wn * 64 + tn * 16 + l15) * 8);
                a = *(const bf16x8*)(As + (wm * 16 + l15) * 136 + kk * 32 + quad * 8);
                #pragma unroll
                for (int tn = 0; tn < 4; ++tn)
                    acc[tn] = __builtin_amdgcn_mfma_f32_16x16x32_bf16(a, b[tn], acc[tn], 0, 0, 0);
            }
            #pragma unroll
            for (int tn = 0; tn < 4; ++tn) {
                int gc = wn * 64 + tn * 16 + l15;
                float shift = b2[gc];
                #pragma unroll
                for (int r = 0; r < 4; ++r) {
                    int gr = m0 + wm * 16 + quad * 4 + r;
                    if (gr < N) {
                        float v = fmaxf(acc[tn][r] + shift, 0.f);
                        Out[(size_t)gr * 128 + gc] = __float2bfloat16(v);
                    }
                }
            }
            __syncthreads();   // As reused by next grid-stride tile
        }
        gg.sync();
    }

    // ---------------- pool (verified k_pool body; 2 chunks per block) -------
    const bf16* hf = (GDEPTH & 1) ? bufB : bufA;
    {
        int sub = tid >> 7, t = tid & 127;
        for (int ch = blockIdx.x * 2 + sub; ch * PCH < N; ch += NB * 2) {
            int base = ch * PCH;
            int end = base + PCH; if (end > N) end = N;
            int gcur = batch[base];
            float acc = 0.f;
            for (int i = base; i < end; ++i) {
                int g = batch[i];
                if (g != gcur) {
                    atomicAdd(&hga[gcur * 128 + t], acc);
                    acc = 0.f; gcur = g;
                }
                acc += __bfloat162float(hf[(size_t)i * 128 + t]);
            }
            atomicAdd(&hga[gcur * 128 + t], acc);
        }
    }
    gg.sync();

    // ---------------- proj + LayerNorm (one graph per block-iteration) -----
    {
        float* prow = (float*)smem;
        float* pred = (float*)(smem + 512);
        for (int g = blockIdx.x; g < G; g += NB) {
            float p = 0.f;
            if (tid < 128) {
                int cntn = gp[g + 1] - gp[g];
                float inv = 1.0f / (float)(cntn < 1 ? 1 : cntn);
                prow[tid] = hga[g * 128 + tid] * inv;
            }
            __syncthreads();
            if (tid < 128) {
                p = bpj[tid];
                #pragma unroll 8
                for (int k = 0; k < 128; ++k) p += prow[k] * Wpj[k * 128 + tid];
                pred[tid] = p;
            }
            __syncthreads();
            for (int o = 64; o > 0; o >>= 1) { if (tid < o) pred[tid] += pred[tid + o]; __syncthreads(); }
            float mu = pred[0] * (1.0f / 128.0f);
            __syncthreads();
            if (tid < 128) pred[tid] = (p - mu) * (p - mu);
            __syncthreads();
            for (int o = 64; o > 0; o >>= 1) { if (tid < o) pred[tid] += pred[tid + o]; __syncthreads(); }
            float var = pred[0] * (1.0f / 128.0f);
            if (tid < 128)
                outp[g * 128 + tid] = (p - mu) * rsqrtf(var + 1e-5f) * lng[tid] + lnb[tid];
            __syncthreads();
        }
    }
}

extern "C" void kernel_launch(void* const* d_in, const int* in_sizes, int n_in,
                              void* d_out, int out_size, void* d_ws, size_t ws_size,
                              hipStream_t stream) {
    const float* x   = (const float*)d_in[0];
    const int*   ei  = (const int*)d_in[1];    // int32: [src(E), dst(E)]
    const int*   bat = (const int*)d_in[2];    // int32, sorted
    const float* W1s = (const float*)d_in[3];
    const float* b1s = (const float*)d_in[4];
    const float* bng = (const float*)d_in[5];
    const float* bnb = (const float*)d_in[6];
    const float* bnm = (const float*)d_in[7];
    const float* bnv = (const float*)d_in[8];
    const float* W2s = (const float*)d_in[9];
    const float* b2s = (const float*)d_in[10];
    const float* Wp  = (const float*)d_in[11];
    const float* bp  = (const float*)d_in[12];
    const float* lng = (const float*)d_in[13];
    const float* lnb = (const float*)d_in[14];
    const int E = in_sizes[1] / 2;
    const int N = in_sizes[2];
    const int G = out_size / 128;

    char* w = (char*)d_ws;
    size_t off = 0;
    auto alloc = [&](size_t b) { char* p = w + off; off += (b + 255) & ~(size_t)255; return p; };
    bf16* buf_a = (bf16*)alloc((size_t)N * 128 * 2);
    bf16* buf_b = (bf16*)alloc((size_t)N * 128 * 2);
    int* col   = (int*)alloc(((size_t)N * CAP + 256) * 4);
    int* fill  = (int*)alloc((size_t)N * 4);          // adjacent to hga:
    float* hga = (float*)alloc((size_t)G * 128 * 4);  // one fused memset below
    int* gp    = (int*)alloc(2048);
    bf16* Wp1  = (bf16*)alloc((size_t)GDEPTH * 16384 * 2);
    bf16* Wp2  = (bf16*)alloc((size_t)GDEPTH * 16384 * 2);
    float* sA  = (float*)alloc((size_t)GDEPTH * 128 * 4);
    float* tA  = (float*)alloc((size_t)GDEPTH * 128 * 4);

    // single memset covers fill + (pad) + hga
    size_t zlen = (size_t)((char*)hga + (size_t)G * 128 * 4 - (char*)fill);
    hipMemsetAsync(fill, 0, zlen, stream);

    const int BCONV = (N * 32 + 255) / 256;
    const int BGB   = (N + 255) / 256;
    const int BCSR  = ((E + CSR_CH - 1) / CSR_CH) * NSLICE;   // sliced bucket scatter
    k_setup<<<384 + BCONV + BGB + BCSR, 256, 0, stream>>>(
        W1s, W2s, b1s, bng, bnb, bnm, bnv, Wp1, Wp2, sA, tA,
        (const float4*)x, (bf162*)buf_a, bat, gp, ei, fill, col, N, E, G, BCONV, BGB, BCSR);

    // cooperative mega kernel: grid clamped by occupancy for guaranteed
    // co-residency (R15/R18: gather throughput insensitive to block count)
    static int s_nb = 0;
    if (s_nb == 0) {
        int mb = 0;
        if (hipOccupancyMaxActiveBlocksPerMultiprocessor(&mb, k_mega, 256, 0) != hipSuccess || mb < 1)
            mb = 4;
        s_nb = mb * 256;
        if (s_nb > 2048) s_nb = 2048;
    }
    int NT = (N + 31) / 32;
    int NB = s_nb;
    float* outp = (float*)d_out;
    void* args[] = {
        (void*)&buf_a, (void*)&buf_b, (void*)&fill, (void*)&col,
        (void*)&Wp1, (void*)&Wp2, (void*)&sA, (void*)&tA,
        (void*)&b2s, (void*)&bat, (void*)&gp, (void*)&hga,
        (void*)&Wp, (void*)&bp, (void*)&lng, (void*)&lnb, (void*)&outp,
        (void*)&N, (void*)&G, (void*)&NT, (void*)&NB
    };
    hipLaunchCooperativeKernel((void*)k_mega, dim3(NB), dim3(256), args, 0, stream);
}

// Round 8
// 445.618 us; speedup vs baseline: 2.0544x; 2.0544x over previous
//
#include <hip/hip_runtime.h>
#include <hip/hip_bf16.h>

// PatchGINEncoder on MI355X.
// R1-R13: see git history. Key: int32 edge inputs; col[node][64] buckets built
//     by sliced atomic scatter in k_setup; fused per-layer aggregate+MLP(MFMA).
// R14 (FAILED): 8-deep gather @ VGPR 68: occupancy cliff, slower.
// R15: 32-row tiles, 4-deep gather, VGPR 40. (476us)
// R16/R17: scatter chunks 2048, interleaved bid%3. k_setup < 85us.
// R18 (FAILED, decisive): 8-deep @ VGPR 56: dur/BW FLAT, occ 53->37%.
//     Gather = per-CU miss-slot (Q~32) x latency bound; FETCH ~193MB is the
//     compulsory floor. k_layer ~85us STRUCTURAL at bf16.
// R19/R20 (FAILED): 64 slice-owner full-E scans: occ 4%, k_setup ~1150us.
// R21: fused fill/hga memset: 472.3us BEST. Per-dispatch overhead ~4us.
// R22 (FAILED, mechanism ID'd): cooperative mega-kernel 915us. grid.sync
//     spin-poll traffic: FETCH 981MB (+370), WRITE 301MB (+210), VALU 6.9%.
//     ~1000 blocks idle-spin per layer round (3125 tiles / 2048 blocks) +
//     tail serialization. Cooperative fusion wrong tool here. Reverted.
// R23: atomic-free pool fused INTO proj: batch is sorted, gp[] gives each
//     graph's contiguous row range -> one block per graph sums h directly
//     (2 row-streams x 128 lanes, unroll-4). Deletes k_pool dispatch, hga
//     buffer + its memset share, all pool atomics. k_setup/k_layer identical
//     to R21.

#define GDEPTH 3
#define CAP 64

typedef __bf16 bf16x8 __attribute__((ext_vector_type(8)));
typedef float  f32x4  __attribute__((ext_vector_type(4)));
typedef __hip_bfloat16  bf16;
typedef __hip_bfloat162 bf162;

#define CSR_CH 2048
#define NSLICE 8
#define NSLICE_LOG 3

// ------- fused setup: bucket scatter (interleaved) | prep | convert x | bounds ----
__global__ void k_setup(const float* __restrict__ W1s, const float* __restrict__ W2s,
                        const float* __restrict__ b1s, const float* __restrict__ bng,
                        const float* __restrict__ bnb, const float* __restrict__ bnm,
                        const float* __restrict__ bnv,
                        bf16* __restrict__ Wp1, bf16* __restrict__ Wp2,
                        float* __restrict__ sArr, float* __restrict__ tArr,
                        const float4* __restrict__ x4, bf162* __restrict__ h,
                        const int* __restrict__ batch, int* __restrict__ gp,
                        const int* __restrict__ ei, int* __restrict__ fill,
                        int* __restrict__ col,
                        int N, int E, int G, int BCONV, int BGB, int BCSR) {
    int bid = blockIdx.x;
    int tid = threadIdx.x;
    if (bid % 3 == 0 && bid / 3 < BCSR) {
        // ---- sliced bucket scatter (atomic/write locality), int4 edge reads ----
        int sb = bid / 3;
        int s = sb & (NSLICE - 1);
        int chunk = sb >> NSLICE_LOG;
        int lo = (int)((long long)s * N / NSLICE);
        int hi = (int)((long long)(s + 1) * N / NSLICE);
        int baseq = chunk * (CSR_CH / 4);
        const int4* d4p = (const int4*)(ei + E);
        const int4* s4p = (const int4*)ei;
        #pragma unroll
        for (int i = 0; i < CSR_CH / 1024; ++i) {
            int q = baseq + i * 256 + tid;
            int e0 = q * 4;
            if (e0 + 3 < E) {
                int4 d4 = d4p[q];
                if ((d4.x >= lo && d4.x < hi) || (d4.y >= lo && d4.y < hi) ||
                    (d4.z >= lo && d4.z < hi) || (d4.w >= lo && d4.w < hi)) {
                    int4 s4 = s4p[q];
                    if (d4.x >= lo && d4.x < hi) { int p = atomicAdd(&fill[d4.x], 1); if (p < CAP) col[(size_t)d4.x * CAP + p] = s4.x; }
                    if (d4.y >= lo && d4.y < hi) { int p = atomicAdd(&fill[d4.y], 1); if (p < CAP) col[(size_t)d4.y * CAP + p] = s4.y; }
                    if (d4.z >= lo && d4.z < hi) { int p = atomicAdd(&fill[d4.z], 1); if (p < CAP) col[(size_t)d4.z * CAP + p] = s4.z; }
                    if (d4.w >= lo && d4.w < hi) { int p = atomicAdd(&fill[d4.w], 1); if (p < CAP) col[(size_t)d4.w * CAP + p] = s4.w; }
                }
            } else if (e0 < E) {
                for (int e = e0; e < E; ++e) {
                    int d = ei[E + e];
                    if (d >= lo && d < hi) {
                        int p = atomicAdd(&fill[d], 1);
                        if (p < CAP) col[(size_t)d * CAP + p] = ei[e];
                    }
                }
            }
        }
        return;
    }
    // compact non-scatter block id: subtract # of scatter bids < bid
    {
        int nsc = (bid + 2) / 3;
        if (nsc > BCSR) nsc = BCSR;
        bid -= nsc;
    }
    if (bid < 384) {
        // ---- weight prep: pack W into B-frag order, fold BN ----
        int idx = bid * 256 + tid;                 // [0, 6*16384)
        int l   = idx / 32768;
        int rem = idx - l * 32768;
        int w   = rem >> 14;
        int p   = rem & 16383;
        int j = p & 7, n = (p >> 3) & 127, tq = p >> 10;
        int quad = tq & 3, kk = tq >> 2;
        int k = kk * 32 + quad * 8 + j;
        const float* W = w ? W2s : W1s;
        bf16* Wp = w ? Wp2 : Wp1;
        Wp[l * 16384 + p] = __float2bfloat16(W[l * 16384 + k * 128 + n]);
        if (idx < GDEPTH * 128) {
            int ll = idx >> 7, c = idx & 127;
            float inv = rsqrtf(bnv[ll * 128 + c] + 1e-5f);
            float s = inv * bng[ll * 128 + c];
            sArr[idx] = s;
            tArr[idx] = (b1s[ll * 128 + c] - bnm[ll * 128 + c]) * s + bnb[ll * 128 + c];
        }
        return;
    }
    bid -= 384;
    if (bid < BCONV) {
        // ---- x -> bf16 ----
        int i = bid * 256 + tid;
        int n4 = N * 32;
        if (i < n4) {
            float4 v = x4[i];
            bf162 a, b;
            a.x = __float2bfloat16(v.x); a.y = __float2bfloat16(v.y);
            b.x = __float2bfloat16(v.z); b.y = __float2bfloat16(v.w);
            h[2 * i] = a; h[2 * i + 1] = b;
        }
        return;
    }
    bid -= BCONV;
    if (bid < BGB) {
        // ---- graph bounds from sorted batch ----
        int i = bid * 256 + tid;
        if (i < N) {
            int b = batch[i];
            if (i == 0) {
                for (int g = 0; g <= b; ++g) gp[g] = 0;
            } else {
                int pb = batch[i - 1];
                if (pb != b) for (int g = pb + 1; g <= b; ++g) gp[g] = i;
            }
            if (i == N - 1) {
                for (int g = b + 1; g <= G; ++g) gp[g] = N;
            }
        }
        return;
    }
}

// -------- fused layer, 32-row tile: z = h + Ah -> relu(BN(zW1+b1))W2+b2, relu ----
__global__ __launch_bounds__(256) void k_layer(const bf16* __restrict__ h,
                                               const int* __restrict__ deg,
                                               const int* __restrict__ col,
                                               const bf16* __restrict__ Bp1,
                                               const bf16* __restrict__ Bp2,
                                               const float* __restrict__ sv,
                                               const float* __restrict__ tv,
                                               const float* __restrict__ b2,
                                               bf16* __restrict__ Out, int M) {
    __shared__ __align__(16) bf16 As[32 * 136];   // +8 pad
    const int tid = threadIdx.x;
    const int m0 = blockIdx.x * 32;
    const int grp = tid >> 4, c = tid & 15;
    const bf16x8* h8 = (const bf16x8*)h;           // row j chunk c at h8[j*16+c]

    #pragma unroll
    for (int it = 0; it < 2; ++it) {
        int row = grp * 2 + it;
        int node = m0 + row;
        float acc[8];
        if (node < M) {
            bf16x8 self = h8[(size_t)node * 16 + c];
            #pragma unroll
            for (int k = 0; k < 8; ++k) acc[k] = (float)self[k];
            int d = deg[node]; if (d > CAP) d = CAP;
            const int* cb = col + (size_t)node * CAP;
            int e = 0;
            for (; e + 3 < d; e += 4) {
                int j0 = cb[e], j1 = cb[e + 1], j2 = cb[e + 2], j3 = cb[e + 3];
                bf16x8 v0 = h8[(size_t)j0 * 16 + c];
                bf16x8 v1 = h8[(size_t)j1 * 16 + c];
                bf16x8 v2 = h8[(size_t)j2 * 16 + c];
                bf16x8 v3 = h8[(size_t)j3 * 16 + c];
                #pragma unroll
                for (int k = 0; k < 8; ++k)
                    acc[k] += ((float)v0[k] + (float)v1[k]) + ((float)v2[k] + (float)v3[k]);
            }
            for (; e < d; ++e) {
                bf16x8 v = h8[(size_t)cb[e] * 16 + c];
                #pragma unroll
                for (int k = 0; k < 8; ++k) acc[k] += (float)v[k];
            }
        } else {
            #pragma unroll
            for (int k = 0; k < 8; ++k) acc[k] = 0.f;
        }
        bf16x8 r;
        #pragma unroll
        for (int k = 0; k < 8; ++k) {
            __hip_bfloat16 t = __float2bfloat16(acc[k]);
            r[k] = *(__bf16*)&t;
        }
        *(bf16x8*)(As + row * 136 + c * 8) = r;
    }
    __syncthreads();

    const int lane = tid & 63;
    const int wid = tid >> 6;
    const int wm = wid & 1, wn = wid >> 1;     // wm: 16-row half; wn: 64-col half
    const int l15 = lane & 15, quad = lane >> 4;

    f32x4 acc[4];
    #pragma unroll
    for (int j = 0; j < 4; ++j) acc[j] = (f32x4){0.f, 0.f, 0.f, 0.f};
    #pragma unroll
    for (int kk = 0; kk < 4; ++kk) {
        bf16x8 a, b[4];
        #pragma unroll
        for (int tn = 0; tn < 4; ++tn)
            b[tn] = *(const bf16x8*)(Bp1 + ((kk * 4 + quad) * 128 + wn * 64 + tn * 16 + l15) * 8);
        a = *(const bf16x8*)(As + (wm * 16 + l15) * 136 + kk * 32 + quad * 8);
        #pragma unroll
        for (int tn = 0; tn < 4; ++tn)
            acc[tn] = __builtin_amdgcn_mfma_f32_16x16x32_bf16(a, b[tn], acc[tn], 0, 0, 0);
    }
    __syncthreads();                               // all GEMM1 A-reads done
    // epilogue1: y = relu(acc*s + t) -> LDS (C/D: col=lane&15, row=quad*4+reg)
    #pragma unroll
    for (int tn = 0; tn < 4; ++tn) {
        int gc = wn * 64 + tn * 16 + l15;
        float scale = sv[gc], shift = tv[gc];
        #pragma unroll
        for (int r = 0; r < 4; ++r) {
            float v = fmaxf(acc[tn][r] * scale + shift, 0.f);
            int row = wm * 16 + quad * 4 + r;
            __hip_bfloat16 t = __float2bfloat16(v);
            As[row * 136 + gc] = *(bf16*)&t;
        }
    }
    __syncthreads();                               // y fully in LDS
    #pragma unroll
    for (int j = 0; j < 4; ++j) acc[j] = (f32x4){0.f, 0.f, 0.f, 0.f};
    #pragma unroll
    for (int kk = 0; kk < 4; ++kk) {
        bf16x8 a, b[4];
        #pragma unroll
        for (int tn = 0; tn < 4; ++tn)
            b[tn] = *(const bf16x8*)(Bp2 + ((kk * 4 + quad) * 128 + wn * 64 + tn * 16 + l15) * 8);
        a = *(const bf16x8*)(As + (wm * 16 + l15) * 136 + kk * 32 + quad * 8);
        #pragma unroll
        for (int tn = 0; tn < 4; ++tn)
            acc[tn] = __builtin_amdgcn_mfma_f32_16x16x32_bf16(a, b[tn], acc[tn], 0, 0, 0);
    }
    // epilogue2: h_next = relu(acc + b2) -> global (different buffer)
    #pragma unroll
    for (int tn = 0; tn < 4; ++tn) {
        int gc = wn * 64 + tn * 16 + l15;
        float shift = b2[gc];
        #pragma unroll
        for (int r = 0; r < 4; ++r) {
            int gr = m0 + wm * 16 + quad * 4 + r;
            if (gr < M) {
                float v = fmaxf(acc[tn][r] + shift, 0.f);
                Out[(size_t)gr * 128 + gc] = __float2bfloat16(v);
            }
        }
    }
}

// ------- fused pool + projection + LayerNorm: one block per graph ----------
// batch is sorted => graph g's rows are h[gp[g]..gp[g+1]). Sum directly
// (2 row-streams x 128 lanes), no atomics, no hga buffer.
__global__ __launch_bounds__(256) void k_proj_ln(const bf16* __restrict__ h,
                                                 const int* __restrict__ gp,
                                                 const float* __restrict__ Wp,
                                                 const float* __restrict__ bp,
                                                 const float* __restrict__ lng,
                                                 const float* __restrict__ lnb,
                                                 float* __restrict__ out) {
    __shared__ float row[128];
    __shared__ float red[256];
    int g = blockIdx.x, tid = threadIdx.x;
    int t = tid & 127, half = tid >> 7;
    int lo = gp[g], hi = gp[g + 1];
    float acc = 0.f;
    #pragma unroll 4
    for (int i = lo + half; i < hi; i += 2)
        acc += __bfloat162float(h[(size_t)i * 128 + t]);
    red[tid] = acc;
    __syncthreads();
    if (tid < 128) {
        int cnt = hi - lo;
        float inv = 1.0f / (float)(cnt < 1 ? 1 : cnt);
        row[t] = (red[t] + red[t + 128]) * inv;
    }
    __syncthreads();
    float p = 0.f;
    if (tid < 128) {
        p = bp[t];
        #pragma unroll 8
        for (int k = 0; k < 128; ++k) p += row[k] * Wp[k * 128 + t];
        red[t] = p;
    }
    __syncthreads();
    for (int o = 64; o > 0; o >>= 1) { if (tid < o) red[tid] += red[tid + o]; __syncthreads(); }
    float mu = red[0] * (1.0f / 128.0f);
    __syncthreads();
    if (tid < 128) red[t] = (p - mu) * (p - mu);
    __syncthreads();
    for (int o = 64; o > 0; o >>= 1) { if (tid < o) red[tid] += red[tid + o]; __syncthreads(); }
    float var = red[0] * (1.0f / 128.0f);
    if (tid < 128)
        out[g * 128 + t] = (p - mu) * rsqrtf(var + 1e-5f) * lng[t] + lnb[t];
}

extern "C" void kernel_launch(void* const* d_in, const int* in_sizes, int n_in,
                              void* d_out, int out_size, void* d_ws, size_t ws_size,
                              hipStream_t stream) {
    const float* x   = (const float*)d_in[0];
    const int*   ei  = (const int*)d_in[1];    // int32: [src(E), dst(E)]
    const int*   bat = (const int*)d_in[2];    // int32, sorted
    const float* W1s = (const float*)d_in[3];
    const float* b1s = (const float*)d_in[4];
    const float* bng = (const float*)d_in[5];
    const float* bnb = (const float*)d_in[6];
    const float* bnm = (const float*)d_in[7];
    const float* bnv = (const float*)d_in[8];
    const float* W2s = (const float*)d_in[9];
    const float* b2s = (const float*)d_in[10];
    const float* Wp  = (const float*)d_in[11];
    const float* bp  = (const float*)d_in[12];
    const float* lng = (const float*)d_in[13];
    const float* lnb = (const float*)d_in[14];
    const int E = in_sizes[1] / 2;
    const int N = in_sizes[2];
    const int G = out_size / 128;

    char* w = (char*)d_ws;
    size_t off = 0;
    auto alloc = [&](size_t b) { char* p = w + off; off += (b + 255) & ~(size_t)255; return p; };
    bf16* buf_a = (bf16*)alloc((size_t)N * 128 * 2);
    bf16* buf_b = (bf16*)alloc((size_t)N * 128 * 2);
    int* col   = (int*)alloc(((size_t)N * CAP + 256) * 4);
    int* fill  = (int*)alloc((size_t)N * 4);
    int* gp    = (int*)alloc(2048);
    bf16* Wp1  = (bf16*)alloc((size_t)GDEPTH * 16384 * 2);
    bf16* Wp2  = (bf16*)alloc((size_t)GDEPTH * 16384 * 2);
    float* sA  = (float*)alloc((size_t)GDEPTH * 128 * 4);
    float* tA  = (float*)alloc((size_t)GDEPTH * 128 * 4);

    hipMemsetAsync(fill, 0, (size_t)N * 4, stream);

    const int BCONV = (N * 32 + 255) / 256;
    const int BGB   = (N + 255) / 256;
    const int BCSR  = ((E + CSR_CH - 1) / CSR_CH) * NSLICE;   // sliced bucket scatter
    k_setup<<<384 + BCONV + BGB + BCSR, 256, 0, stream>>>(
        W1s, W2s, b1s, bng, bnb, bnm, bnv, Wp1, Wp2, sA, tA,
        (const float4*)x, (bf162*)buf_a, bat, gp, ei, fill, col, N, E, G, BCONV, BGB, BCSR);

    const bf16* hcur = buf_a;
    bf16* hnext = buf_b;
    for (int l = 0; l < GDEPTH; ++l) {
        k_layer<<<(N + 31) / 32, 256, 0, stream>>>(hcur, fill, col,
                                                   Wp1 + (size_t)l * 16384,
                                                   Wp2 + (size_t)l * 16384,
                                                   sA + l * 128, tA + l * 128,
                                                   b2s + l * 128, hnext, N);
        bf16* tmp = hnext; hnext = (bf16*)hcur; hcur = tmp;
    }
    k_proj_ln<<<G, 256, 0, stream>>>(hcur, gp, Wp, bp, lng, lnb, (float*)d_out);
}

// Round 9
// 437.379 us; speedup vs baseline: 2.0931x; 1.0188x over previous
//
#include <hip/hip_runtime.h>
#include <hip/hip_bf16.h>

// PatchGINEncoder on MI355X.
// R1-R13: see git history. Key: int32 edge inputs; col[node][64] buckets built
//     by sliced atomic scatter in k_setup; fused per-layer aggregate+MLP(MFMA).
// R14 (FAILED): 8-deep gather @ VGPR 68: occupancy cliff, slower.
// R15: 32-row tiles, 4-deep gather, VGPR 40. (476us)
// R16/R17: scatter chunks 2048, interleaved bid%3. k_setup < 85us.
// R18 (FAILED, decisive): 8-deep @ VGPR 56: dur/BW FLAT, occ 53->37%.
//     Gather = per-CU miss-slot (Q~32) x latency bound; FETCH ~193MB is the
//     compulsory floor. k_layer ~85us STRUCTURAL at bf16.
// R19/R20 (FAILED): 64 slice-owner full-E scans: occ 4%, k_setup ~1150us.
// R21: fused fill/hga memset: 472.3us. Per-dispatch overhead ~4us.
// R22 (FAILED, mechanism ID'd): cooperative mega-kernel 915us: grid.sync
//     spin-poll traffic (+600MB) + tail serialization. Reverted.
// R23: atomic-free pool fused INTO proj (gp[] ranges, direct row sums):
//     445.6us BEST. Pool atomics were costing beyond their dispatch.
// R24: k_proj_ln was left at 1 block/CU x 4 waves x 2 serial row-streams
//     (~195 dependent loads each) — same TLP-starved regime as R7/R19 in
//     miniature. Widen to 1024 threads = 16 waves, 8 pooling streams
//     (stream len ~49, 4x outstanding). Matvec/LN unchanged (128-lane
//     shape; uniform barrier loops are 1024-thread safe).

#define GDEPTH 3
#define CAP 64

typedef __bf16 bf16x8 __attribute__((ext_vector_type(8)));
typedef float  f32x4  __attribute__((ext_vector_type(4)));
typedef __hip_bfloat16  bf16;
typedef __hip_bfloat162 bf162;

#define CSR_CH 2048
#define NSLICE 8
#define NSLICE_LOG 3

// ------- fused setup: bucket scatter (interleaved) | prep | convert x | bounds ----
__global__ void k_setup(const float* __restrict__ W1s, const float* __restrict__ W2s,
                        const float* __restrict__ b1s, const float* __restrict__ bng,
                        const float* __restrict__ bnb, const float* __restrict__ bnm,
                        const float* __restrict__ bnv,
                        bf16* __restrict__ Wp1, bf16* __restrict__ Wp2,
                        float* __restrict__ sArr, float* __restrict__ tArr,
                        const float4* __restrict__ x4, bf162* __restrict__ h,
                        const int* __restrict__ batch, int* __restrict__ gp,
                        const int* __restrict__ ei, int* __restrict__ fill,
                        int* __restrict__ col,
                        int N, int E, int G, int BCONV, int BGB, int BCSR) {
    int bid = blockIdx.x;
    int tid = threadIdx.x;
    if (bid % 3 == 0 && bid / 3 < BCSR) {
        // ---- sliced bucket scatter (atomic/write locality), int4 edge reads ----
        int sb = bid / 3;
        int s = sb & (NSLICE - 1);
        int chunk = sb >> NSLICE_LOG;
        int lo = (int)((long long)s * N / NSLICE);
        int hi = (int)((long long)(s + 1) * N / NSLICE);
        int baseq = chunk * (CSR_CH / 4);
        const int4* d4p = (const int4*)(ei + E);
        const int4* s4p = (const int4*)ei;
        #pragma unroll
        for (int i = 0; i < CSR_CH / 1024; ++i) {
            int q = baseq + i * 256 + tid;
            int e0 = q * 4;
            if (e0 + 3 < E) {
                int4 d4 = d4p[q];
                if ((d4.x >= lo && d4.x < hi) || (d4.y >= lo && d4.y < hi) ||
                    (d4.z >= lo && d4.z < hi) || (d4.w >= lo && d4.w < hi)) {
                    int4 s4 = s4p[q];
                    if (d4.x >= lo && d4.x < hi) { int p = atomicAdd(&fill[d4.x], 1); if (p < CAP) col[(size_t)d4.x * CAP + p] = s4.x; }
                    if (d4.y >= lo && d4.y < hi) { int p = atomicAdd(&fill[d4.y], 1); if (p < CAP) col[(size_t)d4.y * CAP + p] = s4.y; }
                    if (d4.z >= lo && d4.z < hi) { int p = atomicAdd(&fill[d4.z], 1); if (p < CAP) col[(size_t)d4.z * CAP + p] = s4.z; }
                    if (d4.w >= lo && d4.w < hi) { int p = atomicAdd(&fill[d4.w], 1); if (p < CAP) col[(size_t)d4.w * CAP + p] = s4.w; }
                }
            } else if (e0 < E) {
                for (int e = e0; e < E; ++e) {
                    int d = ei[E + e];
                    if (d >= lo && d < hi) {
                        int p = atomicAdd(&fill[d], 1);
                        if (p < CAP) col[(size_t)d * CAP + p] = ei[e];
                    }
                }
            }
        }
        return;
    }
    // compact non-scatter block id: subtract # of scatter bids < bid
    {
        int nsc = (bid + 2) / 3;
        if (nsc > BCSR) nsc = BCSR;
        bid -= nsc;
    }
    if (bid < 384) {
        // ---- weight prep: pack W into B-frag order, fold BN ----
        int idx = bid * 256 + tid;                 // [0, 6*16384)
        int l   = idx / 32768;
        int rem = idx - l * 32768;
        int w   = rem >> 14;
        int p   = rem & 16383;
        int j = p & 7, n = (p >> 3) & 127, tq = p >> 10;
        int quad = tq & 3, kk = tq >> 2;
        int k = kk * 32 + quad * 8 + j;
        const float* W = w ? W2s : W1s;
        bf16* Wp = w ? Wp2 : Wp1;
        Wp[l * 16384 + p] = __float2bfloat16(W[l * 16384 + k * 128 + n]);
        if (idx < GDEPTH * 128) {
            int ll = idx >> 7, c = idx & 127;
            float inv = rsqrtf(bnv[ll * 128 + c] + 1e-5f);
            float s = inv * bng[ll * 128 + c];
            sArr[idx] = s;
            tArr[idx] = (b1s[ll * 128 + c] - bnm[ll * 128 + c]) * s + bnb[ll * 128 + c];
        }
        return;
    }
    bid -= 384;
    if (bid < BCONV) {
        // ---- x -> bf16 ----
        int i = bid * 256 + tid;
        int n4 = N * 32;
        if (i < n4) {
            float4 v = x4[i];
            bf162 a, b;
            a.x = __float2bfloat16(v.x); a.y = __float2bfloat16(v.y);
            b.x = __float2bfloat16(v.z); b.y = __float2bfloat16(v.w);
            h[2 * i] = a; h[2 * i + 1] = b;
        }
        return;
    }
    bid -= BCONV;
    if (bid < BGB) {
        // ---- graph bounds from sorted batch ----
        int i = bid * 256 + tid;
        if (i < N) {
            int b = batch[i];
            if (i == 0) {
                for (int g = 0; g <= b; ++g) gp[g] = 0;
            } else {
                int pb = batch[i - 1];
                if (pb != b) for (int g = pb + 1; g <= b; ++g) gp[g] = i;
            }
            if (i == N - 1) {
                for (int g = b + 1; g <= G; ++g) gp[g] = N;
            }
        }
        return;
    }
}

// -------- fused layer, 32-row tile: z = h + Ah -> relu(BN(zW1+b1))W2+b2, relu ----
__global__ __launch_bounds__(256) void k_layer(const bf16* __restrict__ h,
                                               const int* __restrict__ deg,
                                               const int* __restrict__ col,
                                               const bf16* __restrict__ Bp1,
                                               const bf16* __restrict__ Bp2,
                                               const float* __restrict__ sv,
                                               const float* __restrict__ tv,
                                               const float* __restrict__ b2,
                                               bf16* __restrict__ Out, int M) {
    __shared__ __align__(16) bf16 As[32 * 136];   // +8 pad
    const int tid = threadIdx.x;
    const int m0 = blockIdx.x * 32;
    const int grp = tid >> 4, c = tid & 15;
    const bf16x8* h8 = (const bf16x8*)h;           // row j chunk c at h8[j*16+c]

    #pragma unroll
    for (int it = 0; it < 2; ++it) {
        int row = grp * 2 + it;
        int node = m0 + row;
        float acc[8];
        if (node < M) {
            bf16x8 self = h8[(size_t)node * 16 + c];
            #pragma unroll
            for (int k = 0; k < 8; ++k) acc[k] = (float)self[k];
            int d = deg[node]; if (d > CAP) d = CAP;
            const int* cb = col + (size_t)node * CAP;
            int e = 0;
            for (; e + 3 < d; e += 4) {
                int j0 = cb[e], j1 = cb[e + 1], j2 = cb[e + 2], j3 = cb[e + 3];
                bf16x8 v0 = h8[(size_t)j0 * 16 + c];
                bf16x8 v1 = h8[(size_t)j1 * 16 + c];
                bf16x8 v2 = h8[(size_t)j2 * 16 + c];
                bf16x8 v3 = h8[(size_t)j3 * 16 + c];
                #pragma unroll
                for (int k = 0; k < 8; ++k)
                    acc[k] += ((float)v0[k] + (float)v1[k]) + ((float)v2[k] + (float)v3[k]);
            }
            for (; e < d; ++e) {
                bf16x8 v = h8[(size_t)cb[e] * 16 + c];
                #pragma unroll
                for (int k = 0; k < 8; ++k) acc[k] += (float)v[k];
            }
        } else {
            #pragma unroll
            for (int k = 0; k < 8; ++k) acc[k] = 0.f;
        }
        bf16x8 r;
        #pragma unroll
        for (int k = 0; k < 8; ++k) {
            __hip_bfloat16 t = __float2bfloat16(acc[k]);
            r[k] = *(__bf16*)&t;
        }
        *(bf16x8*)(As + row * 136 + c * 8) = r;
    }
    __syncthreads();

    const int lane = tid & 63;
    const int wid = tid >> 6;
    const int wm = wid & 1, wn = wid >> 1;     // wm: 16-row half; wn: 64-col half
    const int l15 = lane & 15, quad = lane >> 4;

    f32x4 acc[4];
    #pragma unroll
    for (int j = 0; j < 4; ++j) acc[j] = (f32x4){0.f, 0.f, 0.f, 0.f};
    #pragma unroll
    for (int kk = 0; kk < 4; ++kk) {
        bf16x8 a, b[4];
        #pragma unroll
        for (int tn = 0; tn < 4; ++tn)
            b[tn] = *(const bf16x8*)(Bp1 + ((kk * 4 + quad) * 128 + wn * 64 + tn * 16 + l15) * 8);
        a = *(const bf16x8*)(As + (wm * 16 + l15) * 136 + kk * 32 + quad * 8);
        #pragma unroll
        for (int tn = 0; tn < 4; ++tn)
            acc[tn] = __builtin_amdgcn_mfma_f32_16x16x32_bf16(a, b[tn], acc[tn], 0, 0, 0);
    }
    __syncthreads();                               // all GEMM1 A-reads done
    // epilogue1: y = relu(acc*s + t) -> LDS (C/D: col=lane&15, row=quad*4+reg)
    #pragma unroll
    for (int tn = 0; tn < 4; ++tn) {
        int gc = wn * 64 + tn * 16 + l15;
        float scale = sv[gc], shift = tv[gc];
        #pragma unroll
        for (int r = 0; r < 4; ++r) {
            float v = fmaxf(acc[tn][r] * scale + shift, 0.f);
            int row = wm * 16 + quad * 4 + r;
            __hip_bfloat16 t = __float2bfloat16(v);
            As[row * 136 + gc] = *(bf16*)&t;
        }
    }
    __syncthreads();                               // y fully in LDS
    #pragma unroll
    for (int j = 0; j < 4; ++j) acc[j] = (f32x4){0.f, 0.f, 0.f, 0.f};
    #pragma unroll
    for (int kk = 0; kk < 4; ++kk) {
        bf16x8 a, b[4];
        #pragma unroll
        for (int tn = 0; tn < 4; ++tn)
            b[tn] = *(const bf16x8*)(Bp2 + ((kk * 4 + quad) * 128 + wn * 64 + tn * 16 + l15) * 8);
        a = *(const bf16x8*)(As + (wm * 16 + l15) * 136 + kk * 32 + quad * 8);
        #pragma unroll
        for (int tn = 0; tn < 4; ++tn)
            acc[tn] = __builtin_amdgcn_mfma_f32_16x16x32_bf16(a, b[tn], acc[tn], 0, 0, 0);
    }
    // epilogue2: h_next = relu(acc + b2) -> global (different buffer)
    #pragma unroll
    for (int tn = 0; tn < 4; ++tn) {
        int gc = wn * 64 + tn * 16 + l15;
        float shift = b2[gc];
        #pragma unroll
        for (int r = 0; r < 4; ++r) {
            int gr = m0 + wm * 16 + quad * 4 + r;
            if (gr < M) {
                float v = fmaxf(acc[tn][r] + shift, 0.f);
                Out[(size_t)gr * 128 + gc] = __float2bfloat16(v);
            }
        }
    }
}

// ------- fused pool + projection + LayerNorm: one block per graph ----------
// batch is sorted => graph g's rows are h[gp[g]..gp[g+1]). R24: 1024 threads
// = 16 waves, 8 parallel row-streams (TLP for the latency-bound sum).
__global__ __launch_bounds__(1024) void k_proj_ln(const bf16* __restrict__ h,
                                                  const int* __restrict__ gp,
                                                  const float* __restrict__ Wp,
                                                  const float* __restrict__ bp,
                                                  const float* __restrict__ lng,
                                                  const float* __restrict__ lnb,
                                                  float* __restrict__ out) {
    __shared__ float row[128];
    __shared__ float red[1024];
    int g = blockIdx.x, tid = threadIdx.x;
    int t = tid & 127, str = tid >> 7;           // 8 streams of 128 lanes
    int lo = gp[g], hi = gp[g + 1];
    float acc = 0.f;
    #pragma unroll 4
    for (int i = lo + str; i < hi; i += 8)
        acc += __bfloat162float(h[(size_t)i * 128 + t]);
    red[tid] = acc;
    __syncthreads();
    if (tid < 128) {
        int cnt = hi - lo;
        float inv = 1.0f / (float)(cnt < 1 ? 1 : cnt);
        float s = red[t];
        #pragma unroll
        for (int k = 1; k < 8; ++k) s += red[t + k * 128];
        row[t] = s * inv;
    }
    __syncthreads();
    float p = 0.f;
    if (tid < 128) {
        p = bp[t];
        #pragma unroll 8
        for (int k = 0; k < 128; ++k) p += row[k] * Wp[k * 128 + t];
        red[t] = p;
    }
    __syncthreads();
    for (int o = 64; o > 0; o >>= 1) { if (tid < o) red[tid] += red[tid + o]; __syncthreads(); }
    float mu = red[0] * (1.0f / 128.0f);
    __syncthreads();
    if (tid < 128) red[t] = (p - mu) * (p - mu);
    __syncthreads();
    for (int o = 64; o > 0; o >>= 1) { if (tid < o) red[tid] += red[tid + o]; __syncthreads(); }
    float var = red[0] * (1.0f / 128.0f);
    if (tid < 128)
        out[g * 128 + t] = (p - mu) * rsqrtf(var + 1e-5f) * lng[t] + lnb[t];
}

extern "C" void kernel_launch(void* const* d_in, const int* in_sizes, int n_in,
                              void* d_out, int out_size, void* d_ws, size_t ws_size,
                              hipStream_t stream) {
    const float* x   = (const float*)d_in[0];
    const int*   ei  = (const int*)d_in[1];    // int32: [src(E), dst(E)]
    const int*   bat = (const int*)d_in[2];    // int32, sorted
    const float* W1s = (const float*)d_in[3];
    const float* b1s = (const float*)d_in[4];
    const float* bng = (const float*)d_in[5];
    const float* bnb = (const float*)d_in[6];
    const float* bnm = (const float*)d_in[7];
    const float* bnv = (const float*)d_in[8];
    const float* W2s = (const float*)d_in[9];
    const float* b2s = (const float*)d_in[10];
    const float* Wp  = (const float*)d_in[11];
    const float* bp  = (const float*)d_in[12];
    const float* lng = (const float*)d_in[13];
    const float* lnb = (const float*)d_in[14];
    const int E = in_sizes[1] / 2;
    const int N = in_sizes[2];
    const int G = out_size / 128;

    char* w = (char*)d_ws;
    size_t off = 0;
    auto alloc = [&](size_t b) { char* p = w + off; off += (b + 255) & ~(size_t)255; return p; };
    bf16* buf_a = (bf16*)alloc((size_t)N * 128 * 2);
    bf16* buf_b = (bf16*)alloc((size_t)N * 128 * 2);
    int* col   = (int*)alloc(((size_t)N * CAP + 256) * 4);
    int* fill  = (int*)alloc((size_t)N * 4);
    int* gp    = (int*)alloc(2048);
    bf16* Wp1  = (bf16*)alloc((size_t)GDEPTH * 16384 * 2);
    bf16* Wp2  = (bf16*)alloc((size_t)GDEPTH * 16384 * 2);
    float* sA  = (float*)alloc((size_t)GDEPTH * 128 * 4);
    float* tA  = (float*)alloc((size_t)GDEPTH * 128 * 4);

    hipMemsetAsync(fill, 0, (size_t)N * 4, stream);

    const int BCONV = (N * 32 + 255) / 256;
    const int BGB   = (N + 255) / 256;
    const int BCSR  = ((E + CSR_CH - 1) / CSR_CH) * NSLICE;   // sliced bucket scatter
    k_setup<<<384 + BCONV + BGB + BCSR, 256, 0, stream>>>(
        W1s, W2s, b1s, bng, bnb, bnm, bnv, Wp1, Wp2, sA, tA,
        (const float4*)x, (bf162*)buf_a, bat, gp, ei, fill, col, N, E, G, BCONV, BGB, BCSR);

    const bf16* hcur = buf_a;
    bf16* hnext = buf_b;
    for (int l = 0; l < GDEPTH; ++l) {
        k_layer<<<(N + 31) / 32, 256, 0, stream>>>(hcur, fill, col,
                                                   Wp1 + (size_t)l * 16384,
                                                   Wp2 + (size_t)l * 16384,
                                                   sA + l * 128, tA + l * 128,
                                                   b2s + l * 128, hnext, N);
        bf16* tmp = hnext; hnext = (bf16*)hcur; hcur = tmp;
    }
    k_proj_ln<<<G, 1024, 0, stream>>>(hcur, gp, Wp, bp, lng, lnb, (float*)d_out);
}